// Round 11
// baseline (199.862 us; speedup 1.0000x reference)
//
#include <hip/hip_runtime.h>
#include <hip/hip_bf16.h>

// BiPairwiseNegativeCELoss on MI355X.
// Inputs: q, d, nd : [16384, 128] fp32. Output: scalar fp32 loss.
// loss = 0.5 * ( mean(softplus(q.nd_row - q.d_row))
//              + mean(softplus(max_c(q_b . d_c, diag -1e6) - q_b.d_b)) )
//
// R11: LDS-free inbatch. R4-R10 proved the barrier/LDS-staged structure pins
// MfmaUtil at ~47% (m97-plateau behavior). db[col][k] row-major IS the MFMA
// B-fragment layout (same formula as the proven afrag load), so B fragments
// come straight from global (L2/L1-resident: 4 waves/block share cols ->
// L1 sibling reuse). Flat 64-tile K-loop, depth-2 register pipeline,
// MFMA <-> global_load interleaved, vmcnt never drained, zero barriers.

#define BATCH 16384
#define DDIM  128
#define ROWS_PER_BLOCK 256       // 4 waves x 64 rows
#define COLS_PER_BLOCK 1024      // 64 tiles of 16 cols
#define NTILES (COLS_PER_BLOCK / 16)            // 64
#define NCG (BATCH / COLS_PER_BLOCK)            // 16
#define NRG (BATCH / ROWS_PER_BLOCK)            // 64
#define NPREP 2048                               // prep blocks (8 rows each)
#define NRED  64                                 // reduce blocks

typedef __attribute__((ext_vector_type(8))) short bf16x8;   // 8 bf16 = 4 VGPRs
typedef __attribute__((ext_vector_type(4))) float f32x4;

__device__ __forceinline__ float softplus_f(float x) {
    return (x > 0.0f) ? x + log1pf(expf(-x)) : log1pf(expf(x));
}

__device__ __forceinline__ ushort f2bf_rne(float x) {
    unsigned u = __float_as_uint(x);
    unsigned r = (u + 0x7FFFu + ((u >> 16) & 1u)) >> 16;
    return (ushort)r;
}

// ---------------------------------------------------------------------------
// Kernel A: pairwise dots (fp32 exact), loss1 block partials, bf16 casts.
// 2048 blocks x 256 threads. Block owns 8 rows; 32 threads per row.
// ---------------------------------------------------------------------------
__global__ __launch_bounds__(256) void prep_kernel(
    const float* __restrict__ q, const float* __restrict__ d,
    const float* __restrict__ nd,
    ushort* __restrict__ qb, ushort* __restrict__ db,
    float* __restrict__ pos, float* __restrict__ loss1_part)
{
    const int t   = threadIdx.x;
    const int sub = t >> 5;                      // row 0..7 within block
    const int ln  = t & 31;                      // 32 threads per row
    const int row = blockIdx.x * 8 + sub;
    const size_t idx = (size_t)row * DDIM + ln * 4;

    float4 a = *(const float4*)(q  + idx);
    float4 b = *(const float4*)(d  + idx);
    float4 c = *(const float4*)(nd + idx);

    ushort4 o;
    o.x = f2bf_rne(a.x); o.y = f2bf_rne(a.y);
    o.z = f2bf_rne(a.z); o.w = f2bf_rne(a.w);
    *(ushort4*)(qb + idx) = o;
    ushort4 p;
    p.x = f2bf_rne(b.x); p.y = f2bf_rne(b.y);
    p.z = f2bf_rne(b.z); p.w = f2bf_rne(b.w);
    *(ushort4*)(db + idx) = p;

    float ps = a.x * b.x + a.y * b.y + a.z * b.z + a.w * b.w;
    float ns = a.x * c.x + a.y * c.y + a.z * c.z + a.w * c.w;
    ps += __shfl_xor(ps, 1); ps += __shfl_xor(ps, 2);
    ps += __shfl_xor(ps, 4); ps += __shfl_xor(ps, 8);
    ps += __shfl_xor(ps, 16);
    ns += __shfl_xor(ns, 1); ns += __shfl_xor(ns, 2);
    ns += __shfl_xor(ns, 4); ns += __shfl_xor(ns, 8);
    ns += __shfl_xor(ns, 16);

    float contrib = 0.0f;
    if (ln == 0) {
        pos[row] = ps;                     // == scores[b][b], exact fp32
        contrib = softplus_f(ns - ps);
    }
    contrib += __shfl_xor(contrib, 32);    // combine the wave's two rows

    __shared__ float red[4];
    if ((t & 63) == 0) red[t >> 6] = contrib;
    __syncthreads();
    if (t == 0)
        loss1_part[blockIdx.x] = red[0] + red[1] + red[2] + red[3];
}

// ---------------------------------------------------------------------------
// Kernel B: fused GEMM + row-max, LDS-free. 1024 blocks x 256 threads.
// Block (rg = bx&63, cg = bx>>6): rows [rg*256, +256), cols [cg*1024, +1024).
// Wave w owns 64 rows (afrag[4][4] in registers, whole K=128). B fragments
// loaded directly from global (db row-major == B-operand layout); 64 col-
// tiles, depth-2 register pipeline, no barriers/LDS at all.
// ---------------------------------------------------------------------------
__global__ __launch_bounds__(256) void inbatch_kernel(
    const ushort* __restrict__ qb, const ushort* __restrict__ db,
    float* __restrict__ partials)
{
    const int t      = threadIdx.x;
    const int w      = t >> 6;
    const int l      = t & 63;
    const int lane16 = l & 15;
    const int quad   = l >> 4;
    const int rg     = blockIdx.x & 63;
    const int cg     = blockIdx.x >> 6;
    const int rows0  = rg * ROWS_PER_BLOCK + w * 64;   // this wave's 64 rows
    const int col0   = cg * COLS_PER_BLOCK;

    // A fragments: lane l holds Q[rows0 + rs*16 + (l&15)][ks*32 + quad*8 + j]
    bf16x8 afrag[4][4];
#pragma unroll
    for (int rs = 0; rs < 4; ++rs)
#pragma unroll
        for (int ks = 0; ks < 4; ++ks)
            afrag[rs][ks] = *(const bf16x8*)(
                qb + (size_t)(rows0 + rs * 16 + lane16) * DDIM + ks * 32 + quad * 8);

    // B fragment base: lane l reads D[col0 + j*16 + (l&15)][ks*32 + quad*8 ..]
    // (db row-major [col][k] is exactly the B-operand fragment layout).
    const ushort* bp = db + (size_t)(col0 + lane16) * DDIM + quad * 8;
    // tile stride = 16 cols * 128 k = 2048 ushorts; ks stride = 32 ushorts

    float runmax[4][4];
#pragma unroll
    for (int rs = 0; rs < 4; ++rs)
#pragma unroll
        for (int r = 0; r < 4; ++r) runmax[rs][r] = -3.0e38f;

    const f32x4 zinit = {0.0f, 0.0f, 0.0f, 0.0f};

#define LOAD_B(dst, j)                                                     \
    do {                                                                   \
        _Pragma("unroll")                                                  \
        for (int ks = 0; ks < 4; ++ks)                                     \
            dst[ks] = *(const bf16x8*)(bp + (size_t)(j) * 2048 + ks * 32); \
    } while (0)

#define PROC_B(src, j)                                                     \
    do {                                                                   \
        const int ctile = col0 + (j) * 16;                                 \
        _Pragma("unroll")                                                  \
        for (int rs = 0; rs < 4; ++rs) {                                   \
            f32x4 s = __builtin_amdgcn_mfma_f32_16x16x32_bf16(             \
                afrag[rs][0], src[0], zinit, 0, 0, 0);                     \
            _Pragma("unroll")                                              \
            for (int ks = 1; ks < 4; ++ks)                                 \
                s = __builtin_amdgcn_mfma_f32_16x16x32_bf16(               \
                    afrag[rs][ks], src[ks], s, 0, 0, 0);                   \
            if (ctile == rows0 + rs * 16) {    /* diagonal tile: -1e6 */   \
                _Pragma("unroll")                                          \
                for (int r = 0; r < 4; ++r)                                \
                    if (quad * 4 + r == lane16) s[r] -= 1.0e6f;            \
            }                                                              \
            _Pragma("unroll")                                              \
            for (int r = 0; r < 4; ++r)                                    \
                runmax[rs][r] = fmaxf(runmax[rs][r], s[r]);                \
        }                                                                  \
    } while (0)

    bf16x8 bf0[4], bf1[4];
    LOAD_B(bf0, 0);
    LOAD_B(bf1, 1);

    for (int u = 0; u < NTILES / 2; ++u) {       // tiles 2u, 2u+1
        PROC_B(bf0, 2 * u);
        if (u + 1 < NTILES / 2) LOAD_B(bf0, 2 * u + 2);
        PROC_B(bf1, 2 * u + 1);
        if (u + 1 < NTILES / 2) LOAD_B(bf1, 2 * u + 3);
    }
#undef LOAD_B
#undef PROC_B

    // reduce max across the 16 lanes (cols) of each quad-group
#pragma unroll
    for (int rs = 0; rs < 4; ++rs)
#pragma unroll
        for (int r = 0; r < 4; ++r) {
            float m = runmax[rs][r];
            m = fmaxf(m, __shfl_xor(m, 1));
            m = fmaxf(m, __shfl_xor(m, 2));
            m = fmaxf(m, __shfl_xor(m, 4));
            m = fmaxf(m, __shfl_xor(m, 8));
            runmax[rs][r] = m;
        }

    // partial row-max for this col-group -> global [NCG][BATCH]
    if (lane16 == 0) {
#pragma unroll
        for (int rs = 0; rs < 4; ++rs)
#pragma unroll
            for (int r = 0; r < 4; ++r)
                partials[(size_t)cg * BATCH + rows0 + rs * 16 + quad * 4 + r] =
                    runmax[rs][r];
    }
}

// ---------------------------------------------------------------------------
// Kernel C: combine col-group partials, softplus, per-block sums (no atomics).
// ---------------------------------------------------------------------------
__global__ __launch_bounds__(256) void reduce_kernel(
    const float* __restrict__ partials, const float* __restrict__ pos,
    float* __restrict__ red_part)
{
    const int t = threadIdx.x;
    const int r = blockIdx.x * 256 + t;
    float fm = partials[r];
#pragma unroll
    for (int cgi = 1; cgi < NCG; ++cgi)
        fm = fmaxf(fm, partials[(size_t)cgi * BATCH + r]);
    float c = softplus_f(fm - pos[r]);
    c += __shfl_xor(c, 1);  c += __shfl_xor(c, 2);
    c += __shfl_xor(c, 4);  c += __shfl_xor(c, 8);
    c += __shfl_xor(c, 16); c += __shfl_xor(c, 32);

    __shared__ float red[4];
    if ((t & 63) == 0) red[t >> 6] = c;
    __syncthreads();
    if (t == 0)
        red_part[blockIdx.x] = red[0] + red[1] + red[2] + red[3];
}

// ---------------------------------------------------------------------------
// Kernel D: final sum of loss1_part[2048] + red_part[64] -> scalar loss.
// ---------------------------------------------------------------------------
__global__ __launch_bounds__(256) void finalize_kernel(
    const float* __restrict__ loss1_part, const float* __restrict__ red_part,
    float* __restrict__ out)
{
    const int t = threadIdx.x;
    float s = 0.0f;
#pragma unroll
    for (int i = 0; i < NPREP / 256; ++i)
        s += loss1_part[i * 256 + t];
    if (t < NRED) s += red_part[t];
    s += __shfl_xor(s, 1);  s += __shfl_xor(s, 2);
    s += __shfl_xor(s, 4);  s += __shfl_xor(s, 8);
    s += __shfl_xor(s, 16); s += __shfl_xor(s, 32);

    __shared__ float red[4];
    if ((t & 63) == 0) red[t >> 6] = s;
    __syncthreads();
    if (t == 0)
        out[0] = (red[0] + red[1] + red[2] + red[3]) * (1.0f / (2.0f * BATCH));
}

extern "C" void kernel_launch(void* const* d_in, const int* in_sizes, int n_in,
                              void* d_out, int out_size, void* d_ws, size_t ws_size,
                              hipStream_t stream)
{
    const float* q  = (const float*)d_in[0];
    const float* d  = (const float*)d_in[1];
    const float* nd = (const float*)d_in[2];
    float* out = (float*)d_out;

    char* ws = (char*)d_ws;
    float*  pos        = (float*)ws;                                 // 64 KB
    ushort* qb         = (ushort*)(ws + 65536);                      // 4 MB
    ushort* db         = (ushort*)(ws + 65536 + 4194304);            // 4 MB
    float*  partials   = (float*)(ws + 65536 + 2 * 4194304);         // 1 MB
    float*  loss1_part = (float*)(ws + 65536 + 2 * 4194304 + 1048576);     // 8 KB
    float*  red_part   = (float*)(ws + 65536 + 2 * 4194304 + 1048576 + 8192); // 256 B

    prep_kernel<<<NPREP, 256, 0, stream>>>(q, d, nd, qb, db, pos, loss1_part);
    inbatch_kernel<<<NRG * NCG, 256, 0, stream>>>(qb, db, partials);
    reduce_kernel<<<NRED, 256, 0, stream>>>(partials, pos, red_part);
    finalize_kernel<<<1, 256, 0, stream>>>(loss1_part, red_part, out);
}

// Round 12
// 163.837 us; speedup vs baseline: 1.2199x; 1.2199x over previous
//
#include <hip/hip_runtime.h>
#include <hip/hip_bf16.h>

// BiPairwiseNegativeCELoss on MI355X.
// Inputs: q, d, nd : [16384, 128] fp32. Output: scalar fp32 loss.
// loss = 0.5 * ( mean(softplus(q.nd_row - q.d_row))
//              + mean(softplus(max_c(q_b . d_c, diag -1e6) - q_b.d_b)) )
//
// R12: (a) revert to R8's LDS-staged structure (R11 direct-global B was
// latency-bound: 135 µs, MfmaUtil 21%); (b) switch MFMA to 32x32x16
// (8.07 cyc / 32k FLOP vs 4.85 / 16k -> MFMA term 79.5k -> 66k cyc/CU,
// half the issue slots); (c) drop finalize: prep/reduce atomicAdd
// pre-scaled sums into out (4-byte memset node zeroes it).
// Layouts: A row=l&31, k=(l>>5)*8+j; C/D col=lane&31,
// row=(reg&3)+8*(reg>>2)+4*(lane>>5)  [m74/m101-verified family].

#define BATCH 16384
#define DDIM  128
#define ROWS_PER_BLOCK 256       // 4 waves x 64 rows
#define COLS_PER_BLOCK 1024      // 16 col-groups
#define CHUNK_COLS 64            // 16 KB bf16 per chunk buffer
#define NCHUNKS (COLS_PER_BLOCK / CHUNK_COLS)   // 16
#define CHUNK_USHORTS (CHUNK_COLS * DDIM)       // 8192
#define NCG (BATCH / COLS_PER_BLOCK)            // 16
#define NRG (BATCH / ROWS_PER_BLOCK)            // 64
#define NPREP 2048                               // prep blocks (8 rows each)
#define NRED  64                                 // reduce blocks
#define SCALE (1.0f / (2.0f * BATCH))

typedef __attribute__((ext_vector_type(8))) short bf16x8;    // 8 bf16 = 4 VGPRs
typedef __attribute__((ext_vector_type(16))) float f32x16;   // 32x32 C/D

__device__ __forceinline__ float softplus_f(float x) {
    return (x > 0.0f) ? x + log1pf(expf(-x)) : log1pf(expf(x));
}

__device__ __forceinline__ ushort f2bf_rne(float x) {
    unsigned u = __float_as_uint(x);
    unsigned r = (u + 0x7FFFu + ((u >> 16) & 1u)) >> 16;
    return (ushort)r;
}

#define WAITVM(n) do { \
        __builtin_amdgcn_s_waitcnt((n) | (7 << 4) | (15 << 8)); \
        asm volatile("" ::: "memory"); \
    } while (0)

// ---------------------------------------------------------------------------
// Kernel A: pairwise dots (fp32 exact), loss1 -> atomicAdd(out), bf16 casts.
// 2048 blocks x 256 threads. Block owns 8 rows; 32 threads per row.
// ---------------------------------------------------------------------------
__global__ __launch_bounds__(256) void prep_kernel(
    const float* __restrict__ q, const float* __restrict__ d,
    const float* __restrict__ nd,
    ushort* __restrict__ qb, ushort* __restrict__ db,
    float* __restrict__ pos, float* __restrict__ out)
{
    const int t   = threadIdx.x;
    const int sub = t >> 5;                      // row 0..7 within block
    const int ln  = t & 31;                      // 32 threads per row
    const int row = blockIdx.x * 8 + sub;
    const size_t idx = (size_t)row * DDIM + ln * 4;

    float4 a = *(const float4*)(q  + idx);
    float4 b = *(const float4*)(d  + idx);
    float4 c = *(const float4*)(nd + idx);

    ushort4 o;
    o.x = f2bf_rne(a.x); o.y = f2bf_rne(a.y);
    o.z = f2bf_rne(a.z); o.w = f2bf_rne(a.w);
    *(ushort4*)(qb + idx) = o;
    ushort4 p;
    p.x = f2bf_rne(b.x); p.y = f2bf_rne(b.y);
    p.z = f2bf_rne(b.z); p.w = f2bf_rne(b.w);
    *(ushort4*)(db + idx) = p;

    float ps = a.x * b.x + a.y * b.y + a.z * b.z + a.w * b.w;
    float ns = a.x * c.x + a.y * c.y + a.z * c.z + a.w * c.w;
    ps += __shfl_xor(ps, 1); ps += __shfl_xor(ps, 2);
    ps += __shfl_xor(ps, 4); ps += __shfl_xor(ps, 8);
    ps += __shfl_xor(ps, 16);
    ns += __shfl_xor(ns, 1); ns += __shfl_xor(ns, 2);
    ns += __shfl_xor(ns, 4); ns += __shfl_xor(ns, 8);
    ns += __shfl_xor(ns, 16);

    float contrib = 0.0f;
    if (ln == 0) {
        pos[row] = ps;                     // == scores[b][b], exact fp32
        contrib = softplus_f(ns - ps);
    }
    contrib += __shfl_xor(contrib, 32);    // combine the wave's two rows

    __shared__ float red[4];
    if ((t & 63) == 0) red[t >> 6] = contrib;
    __syncthreads();
    if (t == 0)
        atomicAdd(out, (red[0] + red[1] + red[2] + red[3]) * SCALE);
}

// ---------------------------------------------------------------------------
// Kernel B: fused GEMM + row-max, 32x32x16 MFMA. 1024 blocks x 256 threads.
// Block (rg = bx&63, cg = bx>>6): rows [rg*256, +256), cols [cg*1024, +1024).
// Wave w owns 64 rows (afrag[2][8], whole K=128). B staged cooperatively:
// 64-col chunks, 2x16KB LDS double buffer, XOR-swizzled 16B k-segments
// (identical staging to R8: LDS slot s of col c holds global seg s^(c&15)).
// ---------------------------------------------------------------------------
__global__ __launch_bounds__(256) void inbatch_kernel(
    const ushort* __restrict__ qb, const ushort* __restrict__ db,
    float* __restrict__ partials)
{
    __shared__ ushort stg[2][CHUNK_USHORTS];   // 2 x 16 KB

    const int t     = threadIdx.x;
    const int w     = t >> 6;
    const int l     = t & 63;
    const int col32 = l & 31;
    const int half  = l >> 5;
    const int rg    = blockIdx.x & 63;
    const int cg    = blockIdx.x >> 6;
    const int rows0 = rg * ROWS_PER_BLOCK + w * 64;   // this wave's 64 rows
    const int col0  = cg * COLS_PER_BLOCK;

    // A fragments: lane l holds Q[rows0 + rs*32 + (l&31)][kk*16 + (l>>5)*8 + j]
    bf16x8 afrag[2][8];
#pragma unroll
    for (int rs = 0; rs < 2; ++rs)
#pragma unroll
        for (int kk = 0; kk < 8; ++kk)
            afrag[rs][kk] = *(const bf16x8*)(
                qb + (size_t)(rows0 + rs * 32 + col32) * DDIM + kk * 16 + half * 8);

    // staging: thread t handles 16B segments i*256 + t (i = 0..3) per chunk;
    // col = seg>>4, LDS slot = seg&15, global kseg = slot^(col&15)
    const ushort* gsrc[4];
#pragma unroll
    for (int i = 0; i < 4; ++i) {
        int seg = i * 256 + t;
        int c   = seg >> 4;
        int s   = seg & 15;
        gsrc[i] = db + (size_t)(col0 + c) * DDIM + ((s ^ (c & 15)) * 8);
    }

    // ds_read bases (ushort offsets): lane reads col (l&31), global 16B seg
    // g = kk*2 + half  ->  LDS slot = g ^ (col&15)
    int dsbase[8];
#pragma unroll
    for (int kk = 0; kk < 8; ++kk)
        dsbase[kk] = col32 * DDIM + (((kk * 2 + half) ^ (col32 & 15)) * 8);

    float runmax[2][16];
#pragma unroll
    for (int rs = 0; rs < 2; ++rs)
#pragma unroll
        for (int r = 0; r < 16; ++r) runmax[rs][r] = -3.0e38f;

    const f32x16 zinit = {0.0f,0.0f,0.0f,0.0f,0.0f,0.0f,0.0f,0.0f,
                          0.0f,0.0f,0.0f,0.0f,0.0f,0.0f,0.0f,0.0f};

    // prologue: stage chunk 0 into buf 0 (LDS dest wave-uniform + lane*16B)
#pragma unroll
    for (int i = 0; i < 4; ++i)
        __builtin_amdgcn_global_load_lds(
            (const __attribute__((address_space(1))) void*)gsrc[i],
            (__attribute__((address_space(3))) void*)(&stg[0][0] + (i * 256 + w * 64) * 8),
            16, 0, 0);

    for (int ch = 0; ch < NCHUNKS; ++ch) {
        WAITVM(0);
        __syncthreads();                     // chunk ch visible; buf ch^1 free
        if (ch + 1 < NCHUNKS) {              // prefetch next chunk now
#pragma unroll
            for (int i = 0; i < 4; ++i)
                __builtin_amdgcn_global_load_lds(
                    (const __attribute__((address_space(1))) void*)(gsrc[i] + (size_t)(ch + 1) * CHUNK_USHORTS),
                    (__attribute__((address_space(3))) void*)(&stg[(ch + 1) & 1][0] + (i * 256 + w * 64) * 8),
                    16, 0, 0);
        }

        const ushort* buf = &stg[ch & 1][0];
#pragma unroll
        for (int ct = 0; ct < 2; ++ct) {     // two 32-col tiles per chunk
            bf16x8 bfrag[8];
#pragma unroll
            for (int kk = 0; kk < 8; ++kk)
                bfrag[kk] = *(const bf16x8*)(buf + dsbase[kk] + ct * 4096);

            const int ctile = col0 + ch * CHUNK_COLS + ct * 32;
#pragma unroll
            for (int rs = 0; rs < 2; ++rs) {
                f32x16 s = __builtin_amdgcn_mfma_f32_32x32x16_bf16(
                    afrag[rs][0], bfrag[0], zinit, 0, 0, 0);
#pragma unroll
                for (int kk = 1; kk < 8; ++kk)
                    s = __builtin_amdgcn_mfma_f32_32x32x16_bf16(
                        afrag[rs][kk], bfrag[kk], s, 0, 0, 0);
                if (ctile == rows0 + rs * 32) {    // diagonal tile: -1e6
#pragma unroll
                    for (int r = 0; r < 16; ++r) {
                        int row = (r & 3) + 8 * (r >> 2) + 4 * half;
                        if (row == col32) s[r] -= 1.0e6f;
                    }
                }
#pragma unroll
                for (int r = 0; r < 16; ++r)
                    runmax[rs][r] = fmaxf(runmax[rs][r], s[r]);
            }
        }
    }

    // reduce max across the 32 lanes (cols) of each half-wave
#pragma unroll
    for (int rs = 0; rs < 2; ++rs)
#pragma unroll
        for (int r = 0; r < 16; ++r) {
            float m = runmax[rs][r];
            m = fmaxf(m, __shfl_xor(m, 1));
            m = fmaxf(m, __shfl_xor(m, 2));
            m = fmaxf(m, __shfl_xor(m, 4));
            m = fmaxf(m, __shfl_xor(m, 8));
            m = fmaxf(m, __shfl_xor(m, 16));
            runmax[rs][r] = m;
        }

    // partial row-max for this col-group -> global [NCG][BATCH]
    if (col32 == 0) {     // lanes 0 and 32: each owns 16 rows per rs
#pragma unroll
        for (int rs = 0; rs < 2; ++rs)
#pragma unroll
            for (int r = 0; r < 16; ++r)
                partials[(size_t)cg * BATCH + rows0 + rs * 32
                         + (r & 3) + 8 * (r >> 2) + 4 * half] = runmax[rs][r];
    }
}

// ---------------------------------------------------------------------------
// Kernel C: combine col-group partials, softplus, atomicAdd(out) (pre-scaled).
// ---------------------------------------------------------------------------
__global__ __launch_bounds__(256) void reduce_kernel(
    const float* __restrict__ partials, const float* __restrict__ pos,
    float* __restrict__ out)
{
    const int t = threadIdx.x;
    const int r = blockIdx.x * 256 + t;
    float fm = partials[r];
#pragma unroll
    for (int cgi = 1; cgi < NCG; ++cgi)
        fm = fmaxf(fm, partials[(size_t)cgi * BATCH + r]);
    float c = softplus_f(fm - pos[r]);
    c += __shfl_xor(c, 1);  c += __shfl_xor(c, 2);
    c += __shfl_xor(c, 4);  c += __shfl_xor(c, 8);
    c += __shfl_xor(c, 16); c += __shfl_xor(c, 32);

    __shared__ float red[4];
    if ((t & 63) == 0) red[t >> 6] = c;
    __syncthreads();
    if (t == 0)
        atomicAdd(out, (red[0] + red[1] + red[2] + red[3]) * SCALE);
}

extern "C" void kernel_launch(void* const* d_in, const int* in_sizes, int n_in,
                              void* d_out, int out_size, void* d_ws, size_t ws_size,
                              hipStream_t stream)
{
    const float* q  = (const float*)d_in[0];
    const float* d  = (const float*)d_in[1];
    const float* nd = (const float*)d_in[2];
    float* out = (float*)d_out;

    char* ws = (char*)d_ws;
    float*  pos      = (float*)ws;                                 // 64 KB
    ushort* qb       = (ushort*)(ws + 65536);                      // 4 MB
    ushort* db       = (ushort*)(ws + 65536 + 4194304);            // 4 MB
    float*  partials = (float*)(ws + 65536 + 2 * 4194304);         // 1 MB

    hipMemsetAsync(out, 0, sizeof(float), stream);
    prep_kernel<<<NPREP, 256, 0, stream>>>(q, d, nd, qb, db, pos, out);
    inbatch_kernel<<<NRG * NCG, 256, 0, stream>>>(qb, db, partials);
    reduce_kernel<<<NRED, 256, 0, stream>>>(partials, pos, out);
}